// Round 9
// baseline (53.275 us; speedup 1.0000x reference)
//
#include <hip/hip_runtime.h>
#include <hip/hip_bf16.h>

// SkeletalConv via MFMA + LDS staging, single fused kernel.
// x: (16, 25, 65536) f32, W: (48, 16, 16, 3) f32, b: (48, 16) f32
// out: (16, 24, 65534) f32
// out[co,e,t] = 0.5*sum_{j,ci,k} W[2e+j,co,ci,k]*x[ci,e+j,t+k] + 0.5*(b[2e,co]+b[2e+1,co])
//
// Per edge, K-dim kk=(ci,j) is 32 = one mfma_f32_16x16x32_bf16 per tap.
// Block = (edge, 256-col chunk). Stage: coalesced float4 loads of x rows
// (ci,e),(ci,e+1), cvt_pk -> lds[ci][col] = dword(bf16 x[ci,e,col] | bf16
// x[ci,e+1,col]<<16) = fragment k-slot pair (kk=2ci, 2ci+1). W fragments
// built per-lane from 6 aligned float4 loads (no repack kernel). Operands:
// A = X-frag (row=t), B = W-frag (col=co) -> C row=t, col=co -> each
// thread stores 4 consecutive t for one co (2x float2). Epilogue applies
// the 0.5 neighbor-mean and folded bias: out = 0.5*C + bhalf.

#define NJ    25
#define LSEQ  65536
#define NE    24
#define LOUTN (LSEQ - 2)               // 65534 valid t
#define CW    260                      // LDS row width in dwords

typedef __attribute__((ext_vector_type(8))) short bf16x8;
typedef __attribute__((ext_vector_type(4))) float f32x4;

static __device__ __forceinline__ unsigned cvtpk(float lo, float hi) {
    union { __hip_bfloat162 h; unsigned u; } cv;
    cv.h = __float22bfloat162_rn(make_float2(lo, hi));   // v_cvt_pk_bf16_f32
    return cv.u;
}

__global__ __launch_bounds__(256)
void skel_mfma_kernel(const float* __restrict__ x,
                      const float* __restrict__ W,
                      const float* __restrict__ b,
                      float* __restrict__ out)
{
    __shared__ unsigned lds[16 * CW];   // [ci][col] bf16 pair (joint e | e+1)

    const int e   = blockIdx.y;
    const int tb  = blockIdx.x * 256;
    const int tid = threadIdx.x;
    const int l   = tid & 63, wv = tid >> 6;
    const int g   = l >> 4,  lc = l & 15;

    // ---- W fragments (B operand): lane l -> co=lc, slots kk=8g+i ----
    // u[d] = (bf16 W[2e,lc,4g+d,k], bf16 W[2e+1,lc,4g+d,k]); 12 floats per j
    // are contiguous and 16B-aligned -> 3+3 float4 loads.
    const float* wp = W + ((size_t)((2 * e) * 16 + lc) * 16 + 4 * g) * 3;
    f32x4 wj0[3], wj1[3];
    #pragma unroll
    for (int q = 0; q < 3; ++q) {
        wj0[q] = *reinterpret_cast<const f32x4*>(wp + 4 * q);
        wj1[q] = *reinterpret_cast<const f32x4*>(wp + 768 + 4 * q);
    }
    union { unsigned u[4]; bf16x8 v8; } Bw[3];
    #pragma unroll
    for (int d = 0; d < 4; ++d)
        #pragma unroll
        for (int k = 0; k < 3; ++k) {
            const int f = d * 3 + k;            // compile-time after unroll
            Bw[k].u[d] = cvtpk(wj0[f >> 2][f & 3], wj1[f >> 2][f & 3]);
        }
    const float bhalf = 0.5f * (b[(2 * e) * 16 + lc] + b[(2 * e + 1) * 16 + lc]);

    // ---- stage: 16 ci-rows x 256 cols (+2 halo) ----
    {
        const int rp = tid >> 4;                    // ci
        const int q0 = tid & 15;
        const float* xlo = x + (size_t)(rp * NJ + e) * LSEQ + tb;
        #pragma unroll
        for (int s = 0; s < 4; ++s) {
            const int c = 4 * q0 + 64 * s;          // 16B-aligned, never OOB
            float4 lo = *reinterpret_cast<const float4*>(xlo + c);
            float4 hi = *reinterpret_cast<const float4*>(xlo + LSEQ + c);
            uint4 pk;
            pk.x = cvtpk(lo.x, hi.x);
            pk.y = cvtpk(lo.y, hi.y);
            pk.z = cvtpk(lo.z, hi.z);
            pk.w = cvtpk(lo.w, hi.w);
            *reinterpret_cast<uint4*>(&lds[rp * CW + c]) = pk;
        }
    }
    if (tid < 32) {                                 // halo cols 256,257
        const int rp = tid >> 1, h = tid & 1;
        const int gc = min(tb + 256 + h, LSEQ - 1); // clamp (last chunk only)
        const float* xl = x + (size_t)(rp * NJ + e) * LSEQ;
        lds[rp * CW + 256 + h] = cvtpk(xl[gc], xl[gc + LSEQ]);
    }
    __syncthreads();

    // ---- compute: wave wv owns cols wv*64 .. wv*64+63 (4 t-tiles of 16) ----
    #pragma unroll
    for (int tc = 0; tc < 4; ++tc) {
        const int tt0 = wv * 64 + tc * 16;          // tile base col in chunk
        f32x4 C = {0.f, 0.f, 0.f, 0.f};
        #pragma unroll
        for (int k = 0; k < 3; ++k) {
            union { unsigned u[4]; bf16x8 v8; } Ax;
            #pragma unroll
            for (int d = 0; d < 4; ++d)
                Ax.u[d] = lds[(4 * g + d) * CW + tt0 + lc + k];
            C = __builtin_amdgcn_mfma_f32_16x16x32_bf16(Ax.v8, Bw[k].v8, C, 0, 0, 0);
        }

        // C row = t-within-tile = 4g+r, col = co = lc
        const int t0p = tb + tt0 + 4 * g;
        float* op = out + (size_t)(lc * NE + e) * LOUTN + t0p;
        float v0 = fmaf(0.5f, C[0], bhalf);
        float v1 = fmaf(0.5f, C[1], bhalf);
        float v2 = fmaf(0.5f, C[2], bhalf);
        float v3 = fmaf(0.5f, C[3], bhalf);
        if (t0p + 3 < LOUTN) {                      // 8B-aligned float2 pair
            *reinterpret_cast<float2*>(op)     = make_float2(v0, v1);
            *reinterpret_cast<float2*>(op + 2) = make_float2(v2, v3);
        } else {
            if (t0p     < LOUTN) op[0] = v0;
            if (t0p + 1 < LOUTN) op[1] = v1;
            if (t0p + 2 < LOUTN) op[2] = v2;
            if (t0p + 3 < LOUTN) op[3] = v3;
        }
    }
}

extern "C" void kernel_launch(void* const* d_in, const int* in_sizes, int n_in,
                              void* d_out, int out_size, void* d_ws, size_t ws_size,
                              hipStream_t stream)
{
    const float* x = (const float*)d_in[0];
    const float* W = (const float*)d_in[1];
    const float* b = (const float*)d_in[2];
    float* out     = (float*)d_out;

    dim3 grid((LOUTN + 255) / 256, NE);      // 256 x 24 blocks, single launch
    skel_mfma_kernel<<<grid, 256, 0, stream>>>(x, W, b, out);
}

// Round 10
// 42.856 us; speedup vs baseline: 1.2431x; 1.2431x over previous
//
#include <hip/hip_runtime.h>
#include <hip/hip_bf16.h>

// SkeletalConv via MFMA + LDS staging, single fused kernel.
// x: (16, 25, 65536) f32, W: (48, 16, 16, 3) f32, b: (48, 16) f32
// out: (16, 24, 65534) f32
// out[co,e,t] = 0.5*sum_{j,ci,k} W[2e+j,co,ci,k]*x[ci,e+j,t+k] + 0.5*(b[2e,co]+b[2e+1,co])
//
// Per edge, K-dim kk=(ci,j) is 32 = one mfma_f32_16x16x32_bf16 per tap.
// Block = (edge, 256-col chunk). Stage: coalesced float4 loads of x rows
// (ci,e),(ci,e+1), cvt_pk -> lds[ci][col] = dword(bf16 x[ci,e,col] | bf16
// x[ci,e+1,col]<<16) = B-fragment slot d's dword (kk=(ci,j) pair enum).
// A = W-frag built in-kernel per lane (6 aligned float4 loads, L2-hot):
// lane l -> co = l&15, slots kk = 8g+i -> u[d] = pack(W[2e,co,4g+d,k],
// W[2e+1,co,4g+d,k]). C row = co = 4g+r, col = t (lc) -> coalesced dword
// stores (round 9 showed swapped operands scatter stores: 46->53 us).
// Epilogue: out = 0.5*C + 0.5*(b[2e,co]+b[2e+1,co]).

#define NJ    25
#define LSEQ  65536
#define NE    24
#define LOUTN (LSEQ - 2)               // 65534 valid t
#define CW    260                      // LDS row width in dwords

typedef __attribute__((ext_vector_type(8))) short bf16x8;
typedef __attribute__((ext_vector_type(4))) float f32x4;

static __device__ __forceinline__ unsigned cvtpk(float lo, float hi) {
    union { __hip_bfloat162 h; unsigned u; } cv;
    cv.h = __float22bfloat162_rn(make_float2(lo, hi));   // v_cvt_pk_bf16_f32
    return cv.u;
}

__global__ __launch_bounds__(256)
void skel_mfma_kernel(const float* __restrict__ x,
                      const float* __restrict__ W,
                      const float* __restrict__ b,
                      float* __restrict__ out)
{
    __shared__ unsigned lds[16 * CW];   // [ci][col] bf16 pair (joint e | e+1)

    const int e   = blockIdx.y;
    const int tb  = blockIdx.x * 256;
    const int tid = threadIdx.x;
    const int l   = tid & 63, wv = tid >> 6;
    const int g   = l >> 4,  lc = l & 15;

    // ---- A fragments (W): lane l -> co=lc, slots kk=8g+i, 3 taps ----
    // 12 contiguous 16B-aligned floats per j: W[2e+j, lc, 4g..4g+3, 0..2]
    const float* wp = W + ((size_t)((2 * e) * 16 + lc) * 16 + 4 * g) * 3;
    f32x4 wj0[3], wj1[3];
    #pragma unroll
    for (int q = 0; q < 3; ++q) {
        wj0[q] = *reinterpret_cast<const f32x4*>(wp + 4 * q);
        wj1[q] = *reinterpret_cast<const f32x4*>(wp + 768 + 4 * q);
    }
    union { unsigned u[4]; bf16x8 v8; } Aw[3];
    #pragma unroll
    for (int d = 0; d < 4; ++d)
        #pragma unroll
        for (int k = 0; k < 3; ++k) {
            const int f = d * 3 + k;            // compile-time after unroll
            Aw[k].u[d] = cvtpk(wj0[f >> 2][f & 3], wj1[f >> 2][f & 3]);
        }

    // ---- folded bias for rows co = 4g+r ----
    const f32x4 b0 = *reinterpret_cast<const f32x4*>(b + (size_t)(2 * e) * 16 + 4 * g);
    const f32x4 b1 = *reinterpret_cast<const f32x4*>(b + (size_t)(2 * e + 1) * 16 + 4 * g);
    f32x4 bias;
    #pragma unroll
    for (int r = 0; r < 4; ++r) bias[r] = 0.5f * (b0[r] + b1[r]);

    // ---- stage: 16 ci-rows x 256 cols (+2 halo) ----
    {
        const int rp = tid >> 4;                    // ci
        const int q0 = tid & 15;
        const float* xlo = x + (size_t)(rp * NJ + e) * LSEQ + tb;
        #pragma unroll
        for (int s = 0; s < 4; ++s) {
            const int c = 4 * q0 + 64 * s;          // 16B-aligned, never OOB
            float4 lo = *reinterpret_cast<const float4*>(xlo + c);
            float4 hi = *reinterpret_cast<const float4*>(xlo + LSEQ + c);
            uint4 pk;
            pk.x = cvtpk(lo.x, hi.x);
            pk.y = cvtpk(lo.y, hi.y);
            pk.z = cvtpk(lo.z, hi.z);
            pk.w = cvtpk(lo.w, hi.w);
            *reinterpret_cast<uint4*>(&lds[rp * CW + c]) = pk;
        }
    }
    if (tid < 32) {                                 // halo cols 256,257
        const int rp = tid >> 1, h = tid & 1;
        const int gc = min(tb + 256 + h, LSEQ - 1); // clamp (last chunk only)
        const float* xl = x + (size_t)(rp * NJ + e) * LSEQ;
        lds[rp * CW + 256 + h] = cvtpk(xl[gc], xl[gc + LSEQ]);
    }
    __syncthreads();

    // ---- compute: wave wv owns cols wv*64 .. wv*64+63 (4 t-tiles of 16) ----
    #pragma unroll
    for (int tc = 0; tc < 4; ++tc) {
        const int cb = wv * 64 + tc * 16 + lc;      // col within chunk
        f32x4 C = {0.f, 0.f, 0.f, 0.f};
        #pragma unroll
        for (int k = 0; k < 3; ++k) {
            union { unsigned u[4]; bf16x8 v8; } Bx;
            #pragma unroll
            for (int d = 0; d < 4; ++d)
                Bx.u[d] = lds[(4 * g + d) * CW + cb + k];
            C = __builtin_amdgcn_mfma_f32_16x16x32_bf16(Aw[k].v8, Bx.v8, C, 0, 0, 0);
        }

        // C row = co = 4g+r, col = t = tb+cb -> coalesced dword stores
        const int t = tb + cb;
        if (t < LOUTN) {
            #pragma unroll
            for (int r = 0; r < 4; ++r)
                out[(size_t)((4 * g + r) * NE + e) * LOUTN + t] = fmaf(0.5f, C[r], bias[r]);
        }
    }
}

extern "C" void kernel_launch(void* const* d_in, const int* in_sizes, int n_in,
                              void* d_out, int out_size, void* d_ws, size_t ws_size,
                              hipStream_t stream)
{
    const float* x = (const float*)d_in[0];
    const float* W = (const float*)d_in[1];
    const float* b = (const float*)d_in[2];
    float* out     = (float*)d_out;

    dim3 grid((LOUTN + 255) / 256, NE);      // 256 x 24 blocks, single launch
    skel_mfma_kernel<<<grid, 256, 0, stream>>>(x, W, b, out);
}